// Round 1
// baseline (3993.303 us; speedup 1.0000x reference)
//
#include <hip/hip_runtime.h>
#include <hip/hip_bf16.h>
#include <math.h>

#define T_LEN 1024
#define NB    128
#define L_SEQ 200
#define EMB   128
#define KSZ   128
#define VSZ   128
#define HID   512
#define G1    2048   // 4*HID
#define G2    512    // 4*KSZ
#define VOCAB 34
#define KK1   768    // EMB + VSZ + HID   (combined K for LSTM1 gates)
#define KK2   640    // HID + KSZ         (combined K for LSTM2 gates)
#define LB    10     // l-rows per attention block (200 = 20 chunks)

typedef __attribute__((ext_vector_type(8))) short bf16x8;  // 8 bf16 = 4 VGPRs
typedef __attribute__((ext_vector_type(4))) float f32x4;

__device__ __forceinline__ float sig_(float x) { return 1.0f / (1.0f + __expf(-x)); }

__device__ __forceinline__ f32x4 MFMA_BF16(bf16x8 a, bf16x8 b, f32x4 c) {
    return __builtin_amdgcn_mfma_f32_16x16x32_bf16(a, b, c, 0, 0, 0);
}
__device__ __forceinline__ bf16x8 LD8(const __hip_bfloat16* p) {
    return *(const bf16x8*)p;
}

// ---------------- prep: combined bf16 weights, biases, zeroed states ----------
__global__ __launch_bounds__(256) void prep_kernel(
    const float* __restrict__ Wih1, const float* __restrict__ Whh1,
    const float* __restrict__ bih1, const float* __restrict__ bhh1,
    const float* __restrict__ Wih2, const float* __restrict__ Whh2,
    const float* __restrict__ bih2, const float* __restrict__ bhh2,
    __hip_bfloat16* __restrict__ Wc1, __hip_bfloat16* __restrict__ Wc2,
    float* __restrict__ bb1, float* __restrict__ bb2,
    __hip_bfloat16* __restrict__ h1b, __hip_bfloat16* __restrict__ h2b,
    float* __restrict__ c1, float* __restrict__ c2)
{
    const int gid = blockIdx.x * 256 + threadIdx.x;
    if (gid < G1 * KK1) {
        const int o = gid / KK1, k = gid - o * KK1;
        const float v = (k < 256) ? Wih1[o * 256 + k] : Whh1[o * 512 + (k - 256)];
        Wc1[gid] = __float2bfloat16(v);
    }
    if (gid < G2 * KK2) {
        const int o = gid / KK2, k = gid - o * KK2;
        const float v = (k < 512) ? Wih2[o * 512 + k] : Whh2[o * 128 + (k - 512)];
        Wc2[gid] = __float2bfloat16(v);
    }
    if (gid < G1) bb1[gid] = bih1[gid] + bhh1[gid];
    if (gid < G2) bb2[gid] = bih2[gid] + bhh2[gid];
    if (gid < 2 * NB * HID) h1b[gid] = __float2bfloat16(0.0f);
    if (gid < 2 * NB * KSZ) h2b[gid] = __float2bfloat16(0.0f);
    if (gid < NB * HID) c1[gid] = 0.0f;
    if (gid < NB * KSZ) c2[gid] = 0.0f;
}

// ---------------- key transpose (T,N,K) -> (N,K,T) ----------------------------
__global__ __launch_bounds__(256) void transpose_key(
    const float* __restrict__ key, float* __restrict__ keyT2)
{
    __shared__ float tl[32][129];
    const int n = blockIdx.x >> 5;
    const int t0 = (blockIdx.x & 31) << 5;
    for (int idx = threadIdx.x; idx < 32 * 128; idx += 256) {
        const int ti = idx >> 7, k = idx & 127;
        tl[ti][k] = key[((size_t)(t0 + ti) * NB + n) * KSZ + k];
    }
    __syncthreads();
    for (int idx = threadIdx.x; idx < 32 * 128; idx += 256) {
        const int k = idx >> 5, ti = idx & 31;
        keyT2[((size_t)n * KSZ + k) * T_LEN + t0 + ti] = tl[ti][k];
    }
}

// ---------------- teacher-forced embedding gather -----------------------------
__global__ __launch_bounds__(256) void ce_gather(
    const int* __restrict__ text, const float* __restrict__ emb,
    float* __restrict__ ce_f, __hip_bfloat16* __restrict__ ce_b)
{
    const int idx = blockIdx.x * 256 + threadIdx.x;   // exact: L*N*128
    const int k = idx & 127;
    const int rn = idx >> 7;
    const int nn = rn & 127;
    const int s = rn >> 7;
    if (s >= L_SEQ) return;
    const int tok = (s == 0) ? 0 : text[nn * L_SEQ + (s - 1)];
    const float v = emb[(size_t)tok * EMB + k];
    ce_f[idx] = v;
    ce_b[idx] = __float2bfloat16(v);
}

// ---------------- q = src @ Wq.T + bq  (rows = L*N) ---------------------------
__global__ __launch_bounds__(256) void qproj_kernel(
    const float* __restrict__ src, const float* __restrict__ Wq,
    const float* __restrict__ bq, float* __restrict__ dst)
{
    __shared__ float xs[2][KSZ];
    const int tid = threadIdx.x;
    const int r0 = blockIdx.x * 2;
    xs[tid >> 7][tid & 127] = src[(size_t)(r0 + (tid >> 7)) * KSZ + (tid & 127)];
    __syncthreads();
    const int sub = tid >> 7, o = tid & 127;
    const float* wr = Wq + (size_t)o * KSZ;
    float acc = bq[o];
    #pragma unroll 8
    for (int k = 0; k < KSZ; k += 4) {
        const float4 w4 = *(const float4*)&wr[k];
        const float4 x4 = *(const float4*)&xs[sub][k];
        acc += w4.x * x4.x + w4.y * x4.y + w4.z * x4.z + w4.w * x4.w;
    }
    dst[(size_t)(r0 + sub) * KSZ + o] = acc;
}

// ---------------- masked attention: ctx = softmax(q.K^T) @ V ------------------
__global__ __launch_bounds__(256) void attn_kernel(
    const float* __restrict__ q,      // [L][N][KSZ]
    const float* __restrict__ keyT2,  // [N][KSZ][T]
    const float* __restrict__ values, // [T][N][VSZ]
    const int* __restrict__ rlen,
    float* __restrict__ ctx_f,        // [L][N][VSZ]
    __hip_bfloat16* __restrict__ ctx_b)
{
    __shared__ float q_s[LB][KSZ];
    __shared__ float e_s[LB][T_LEN];
    __shared__ float cpart[2][LB][VSZ];
    __shared__ float inv_s[LB];
    __shared__ float red[8];
    const int tid = threadIdx.x;
    const int n = blockIdx.x / 20;
    const int s0 = (blockIdx.x % 20) * LB;
    const int len = rlen[n];
    const int lenp = (len + 7) & ~7;

    for (int idx = tid; idx < LB * KSZ; idx += 256) {
        const int j = idx >> 7, k = idx & 127;
        q_s[j][k] = q[((size_t)(s0 + j) * NB + n) * KSZ + k];
    }
    __syncthreads();

    // phase 1: energies (thread owns t = tid + ti*256), skip fully-masked tiles
    {
        const int nt = (len + 255) >> 8;
        float e[4][LB];
        #pragma unroll
        for (int ti = 0; ti < 4; ++ti)
            #pragma unroll
            for (int j = 0; j < LB; ++j) e[ti][j] = 0.0f;
        const float* kb = keyT2 + (size_t)n * KSZ * T_LEN + tid;
        for (int k = 0; k < KSZ; k += 4) {
            float4 q4[LB];
            #pragma unroll
            for (int j = 0; j < LB; ++j) q4[j] = *(const float4*)&q_s[j][k];
            #pragma unroll
            for (int ti = 0; ti < 4; ++ti) {
                if (ti < nt) {
                    const float* kp = kb + ti * 256;
                    const float k0 = kp[(size_t)(k + 0) * T_LEN];
                    const float k1 = kp[(size_t)(k + 1) * T_LEN];
                    const float k2 = kp[(size_t)(k + 2) * T_LEN];
                    const float k3 = kp[(size_t)(k + 3) * T_LEN];
                    #pragma unroll
                    for (int j = 0; j < LB; ++j)
                        e[ti][j] += k0 * q4[j].x + k1 * q4[j].y + k2 * q4[j].z + k3 * q4[j].w;
                }
            }
        }
        #pragma unroll
        for (int ti = 0; ti < 4; ++ti) {
            const int t = tid + ti * 256;
            if (t < len) {
                #pragma unroll
                for (int j = 0; j < LB; ++j) e_s[j][t] = e[ti][j];
            }
        }
    }
    __syncthreads();

    // phase 2: masked softmax per l-row (pad p=0 up to multiple of 8)
    const int wid = tid >> 6, ln = tid & 63;
    for (int j = 0; j < LB; ++j) {
        float m = -3.0e38f;
        for (int t = tid; t < len; t += 256) m = fmaxf(m, e_s[j][t]);
        #pragma unroll
        for (int off = 32; off > 0; off >>= 1) m = fmaxf(m, __shfl_xor(m, off, 64));
        if (ln == 0) red[wid] = m;
        __syncthreads();
        m = fmaxf(fmaxf(red[0], red[1]), fmaxf(red[2], red[3]));
        float s = 0.0f;
        for (int t = tid; t < len; t += 256) {
            const float p = __expf(e_s[j][t] - m);
            e_s[j][t] = p;
            s += p;
        }
        for (int t = len + tid; t < lenp; t += 256) e_s[j][t] = 0.0f;
        #pragma unroll
        for (int off = 32; off > 0; off >>= 1) s += __shfl_xor(s, off, 64);
        if (ln == 0) red[4 + wid] = s;
        __syncthreads();
        if (tid == 0) inv_s[j] = 1.0f / (red[4] + red[5] + red[6] + red[7]);
        __syncthreads();
    }

    // phase 3: ctx = P @ V
    {
        const int half = tid >> 7;
        const int v = tid & 127;
        float acc[LB];
        #pragma unroll
        for (int j = 0; j < LB; ++j) acc[j] = 0.0f;
        for (int tq = 4 * half; tq < lenp; tq += 8) {
            const float* vp = values + ((size_t)tq * NB + n) * VSZ + v;
            const float v0 = vp[0];
            const float v1 = vp[(size_t)NB * VSZ];
            const float v2 = vp[(size_t)2 * NB * VSZ];
            const float v3 = vp[(size_t)3 * NB * VSZ];
            #pragma unroll
            for (int j = 0; j < LB; ++j) {
                const float4 p4 = *(const float4*)&e_s[j][tq];
                acc[j] += p4.x * v0 + p4.y * v1 + p4.z * v2 + p4.w * v3;
            }
        }
        #pragma unroll
        for (int j = 0; j < LB; ++j) cpart[half][j][v] = acc[j];
    }
    __syncthreads();
    for (int idx = tid; idx < LB * VSZ; idx += 256) {
        const int j = idx >> 7, v = idx & 127;
        const float r = (cpart[0][j][v] + cpart[1][j][v]) * inv_s[j];
        const size_t o = ((size_t)(s0 + j) * NB + n) * VSZ + v;
        ctx_f[o] = r;
        ctx_b[o] = __float2bfloat16(r);
    }
}

// ---------------- one scan phase: h2(s)=LSTM2(h1(s)) and h1(s+1)=LSTM1 --------
// phase i: reads h1b[i&1]=h1(i-1), h2b[i&1]=h2(i-2); writes the other buffers.
// blocks 0..31  : gates2 for step s2=i-1 (skipped when i==0)
// blocks 32..159: gates1 producing h1(i) (skipped when i==200)
__global__ __launch_bounds__(256) void scan_phase(
    const int i,
    const __hip_bfloat16* __restrict__ Wc1, const __hip_bfloat16* __restrict__ Wc2,
    const float* __restrict__ bb1, const float* __restrict__ bb2,
    const __hip_bfloat16* __restrict__ ce_b, const __hip_bfloat16* __restrict__ ctx1_b,
    __hip_bfloat16* __restrict__ h1b, __hip_bfloat16* __restrict__ h2b,
    float* __restrict__ c1, float* __restrict__ c2,
    float* __restrict__ h2_all)
{
    const int tid = threadIdx.x;
    const int w = tid >> 6;
    const int lane = tid & 63;
    const int lrow = lane & 15;
    const int krow = (lane >> 4) * 8;
    const int rb = i & 1;
    const __hip_bfloat16* h1r = h1b + (size_t)rb * NB * HID;
    __hip_bfloat16* h1w = h1b + (size_t)(rb ^ 1) * NB * HID;
    const __hip_bfloat16* h2r = h2b + (size_t)rb * NB * KSZ;
    __hip_bfloat16* h2w = h2b + (size_t)(rb ^ 1) * NB * KSZ;
    __shared__ float gl[4][32][17];

    if (blockIdx.x < 32) {
        if (i == 0) return;
        const int s2 = i - 1;
        const int n0 = (blockIdx.x >> 3) * 32;
        const int og = blockIdx.x & 7;
        const int col = w * 128 + og * 16 + lrow;         // row of Wc2 (gate w)
        const __hip_bfloat16* brow = Wc2 + (size_t)col * KK2 + krow;
        const int n_a = n0 + lrow;
        const __hip_bfloat16* a0 = h1r + (size_t)n_a * HID + krow;
        const __hip_bfloat16* a1 = h1r + (size_t)(n_a + 16) * HID + krow;
        const __hip_bfloat16* g0 = h2r + (size_t)n_a * KSZ + krow;
        const __hip_bfloat16* g1 = h2r + (size_t)(n_a + 16) * KSZ + krow;
        f32x4 acc0 = {0.f, 0.f, 0.f, 0.f}, acc1 = {0.f, 0.f, 0.f, 0.f};
        #pragma unroll
        for (int kk = 0; kk < 16; ++kk) {
            const bf16x8 bf = LD8(brow + kk * 32);
            acc0 = MFMA_BF16(LD8(a0 + kk * 32), bf, acc0);
            acc1 = MFMA_BF16(LD8(a1 + kk * 32), bf, acc1);
        }
        #pragma unroll
        for (int kk = 0; kk < 4; ++kk) {
            const bf16x8 bf = LD8(brow + 512 + kk * 32);
            acc0 = MFMA_BF16(LD8(g0 + kk * 32), bf, acc0);
            acc1 = MFMA_BF16(LD8(g1 + kk * 32), bf, acc1);
        }
        const int rbase = (lane >> 4) * 4;
        #pragma unroll
        for (int r = 0; r < 4; ++r) {
            gl[w][rbase + r][lrow] = acc0[r];
            gl[w][16 + rbase + r][lrow] = acc1[r];
        }
        __syncthreads();
        #pragma unroll
        for (int it = 0; it < 2; ++it) {
            const int idx = tid + it * 256;
            const int nl = idx >> 4, oo = idx & 15;
            const int oc = og * 16 + oo;                  // 0..127
            const float iv = gl[0][nl][oo] + bb2[oc];
            const float fv = gl[1][nl][oo] + bb2[128 + oc];
            const float gv = gl[2][nl][oo] + bb2[256 + oc];
            const float ov = gl[3][nl][oo] + bb2[384 + oc];
            const int nn = n0 + nl;
            const float cold = c2[nn * KSZ + oc];
            const float cn = sig_(fv) * cold + sig_(iv) * tanhf(gv);
            const float hn = sig_(ov) * tanhf(cn);
            c2[nn * KSZ + oc] = cn;
            h2w[nn * KSZ + oc] = __float2bfloat16(hn);
            h2_all[((size_t)s2 * NB + nn) * KSZ + oc] = hn;
        }
    } else {
        if (i >= L_SEQ) return;                           // i==200: no gates1
        const int bid2 = blockIdx.x - 32;
        const int n0 = (bid2 >> 5) * 32;
        const int og = bid2 & 31;
        const int col = w * 512 + og * 16 + lrow;         // row of Wc1 (gate w)
        const __hip_bfloat16* brow = Wc1 + (size_t)col * KK1 + krow;
        const int n_a = n0 + lrow;
        const __hip_bfloat16* e0 = ce_b + ((size_t)i * NB + n_a) * EMB + krow;
        const __hip_bfloat16* e1 = ce_b + ((size_t)i * NB + n_a + 16) * EMB + krow;
        const __hip_bfloat16* x0 = ctx1_b + ((size_t)i * NB + n_a) * VSZ + krow;
        const __hip_bfloat16* x1 = ctx1_b + ((size_t)i * NB + n_a + 16) * VSZ + krow;
        const __hip_bfloat16* a0 = h1r + (size_t)n_a * HID + krow;
        const __hip_bfloat16* a1 = h1r + (size_t)(n_a + 16) * HID + krow;
        f32x4 acc0 = {0.f, 0.f, 0.f, 0.f}, acc1 = {0.f, 0.f, 0.f, 0.f};
        #pragma unroll
        for (int kk = 0; kk < 4; ++kk) {
            const bf16x8 bf = LD8(brow + kk * 32);
            acc0 = MFMA_BF16(LD8(e0 + kk * 32), bf, acc0);
            acc1 = MFMA_BF16(LD8(e1 + kk * 32), bf, acc1);
        }
        #pragma unroll
        for (int kk = 0; kk < 4; ++kk) {
            const bf16x8 bf = LD8(brow + 128 + kk * 32);
            acc0 = MFMA_BF16(LD8(x0 + kk * 32), bf, acc0);
            acc1 = MFMA_BF16(LD8(x1 + kk * 32), bf, acc1);
        }
        #pragma unroll
        for (int kk = 0; kk < 16; ++kk) {
            const bf16x8 bf = LD8(brow + 256 + kk * 32);
            acc0 = MFMA_BF16(LD8(a0 + kk * 32), bf, acc0);
            acc1 = MFMA_BF16(LD8(a1 + kk * 32), bf, acc1);
        }
        const int rbase = (lane >> 4) * 4;
        #pragma unroll
        for (int r = 0; r < 4; ++r) {
            gl[w][rbase + r][lrow] = acc0[r];
            gl[w][16 + rbase + r][lrow] = acc1[r];
        }
        __syncthreads();
        #pragma unroll
        for (int it = 0; it < 2; ++it) {
            const int idx = tid + it * 256;
            const int nl = idx >> 4, oo = idx & 15;
            const int oc = og * 16 + oo;                  // 0..511
            const float iv = gl[0][nl][oo] + bb1[oc];
            const float fv = gl[1][nl][oo] + bb1[512 + oc];
            const float gv = gl[2][nl][oo] + bb1[1024 + oc];
            const float ov = gl[3][nl][oo] + bb1[1536 + oc];
            const int nn = n0 + nl;
            const float cold = c1[nn * HID + oc];
            const float cn = sig_(fv) * cold + sig_(iv) * tanhf(gv);
            const float hn = sig_(ov) * tanhf(cn);
            c1[nn * HID + oc] = cn;
            h1w[nn * HID + oc] = __float2bfloat16(hn);
        }
    }
}

// ---------------- out = hardtanh([h2,ctx2]@Wfc.T+bfc); pred = out@emb.T+b_out -
__global__ __launch_bounds__(256) void outpred_kernel(
    const float* __restrict__ h2_all, const float* __restrict__ ctx2,
    const float* __restrict__ Wfc, const float* __restrict__ bfc,
    const float* __restrict__ emb, const float* __restrict__ b_out,
    float* __restrict__ out)
{
    __shared__ float xs[2][256];
    __shared__ float os[2][EMB];
    const int tid = threadIdx.x;
    const int r0 = blockIdx.x * 2;
    const int sub = tid >> 7, lane = tid & 127;
    const int r = r0 + sub;                               // r = s*NB + n
    xs[sub][lane] = h2_all[(size_t)r * KSZ + lane];
    xs[sub][128 + lane] = ctx2[(size_t)r * VSZ + lane];
    __syncthreads();
    const float* wr = Wfc + (size_t)lane * 256;
    float acc = bfc[lane];
    #pragma unroll 8
    for (int k = 0; k < 256; k += 4) {
        const float4 w4 = *(const float4*)&wr[k];
        const float4 x4 = *(const float4*)&xs[sub][k];
        acc += w4.x * x4.x + w4.y * x4.y + w4.z * x4.z + w4.w * x4.w;
    }
    acc = fminf(1.0f, fmaxf(-1.0f, acc));
    os[sub][lane] = acc;
    __syncthreads();
    if (lane < VOCAB) {
        const float* er = emb + (size_t)lane * EMB;
        float a = b_out[lane];
        #pragma unroll 8
        for (int e = 0; e < EMB; e += 4) {
            const float4 e4 = *(const float4*)&er[e];
            const float4 x4 = *(const float4*)&os[sub][e];
            a += e4.x * x4.x + e4.y * x4.y + e4.z * x4.z + e4.w * x4.w;
        }
        const int s = r >> 7, nn = r & 127;
        out[((size_t)nn * L_SEQ + s) * VOCAB + lane] = a;
    }
}

extern "C" void kernel_launch(void* const* d_in, const int* in_sizes, int n_in,
                              void* d_out, int out_size, void* d_ws, size_t ws_size,
                              hipStream_t stream)
{
    (void)in_sizes; (void)n_in; (void)out_size; (void)ws_size;
    const float* key_proj = (const float*)d_in[0];
    const float* values   = (const float*)d_in[1];
    const int*   rlen     = (const int*)d_in[2];
    const int*   text     = (const int*)d_in[3];
    const float* emb      = (const float*)d_in[4];
    const float* Wq    = (const float*)d_in[5];
    const float* bq    = (const float*)d_in[6];
    const float* Wih1  = (const float*)d_in[7];
    const float* Whh1  = (const float*)d_in[8];
    const float* bih1  = (const float*)d_in[9];
    const float* bhh1  = (const float*)d_in[10];
    const float* Wih2  = (const float*)d_in[11];
    const float* Whh2  = (const float*)d_in[12];
    const float* bih2  = (const float*)d_in[13];
    const float* bhh2  = (const float*)d_in[14];
    const float* Wfc   = (const float*)d_in[15];
    const float* bfc   = (const float*)d_in[16];
    const float* b_out = (const float*)d_in[17];
    float* out = (float*)d_out;

    char* p = (char*)d_ws;
    auto take = [&p](size_t bytes) -> char* {
        char* r = p;
        p += (bytes + 255) & ~((size_t)255);
        return r;
    };
    float* keyT2 = (float*)take((size_t)NB * KSZ * T_LEN * 4);       // 64 MB
    float* ce_f  = (float*)take((size_t)L_SEQ * NB * EMB * 4);       // 13 MB
    __hip_bfloat16* ce_b  = (__hip_bfloat16*)take((size_t)L_SEQ * NB * EMB * 2);
    __hip_bfloat16* ctx_b = (__hip_bfloat16*)take((size_t)L_SEQ * NB * VSZ * 2);
    float* ctx_f  = (float*)take((size_t)L_SEQ * NB * VSZ * 4);
    float* qbuf   = (float*)take((size_t)L_SEQ * NB * KSZ * 4);
    float* h2_all = (float*)take((size_t)L_SEQ * NB * KSZ * 4);
    __hip_bfloat16* Wc1 = (__hip_bfloat16*)take((size_t)G1 * KK1 * 2);
    __hip_bfloat16* Wc2 = (__hip_bfloat16*)take((size_t)G2 * KK2 * 2);
    float* bb1 = (float*)take(G1 * 4);
    float* bb2 = (float*)take(G2 * 4);
    __hip_bfloat16* h1b = (__hip_bfloat16*)take((size_t)2 * NB * HID * 2);
    __hip_bfloat16* h2b = (__hip_bfloat16*)take((size_t)2 * NB * KSZ * 2);
    float* c1 = (float*)take((size_t)NB * HID * 4);
    float* c2 = (float*)take((size_t)NB * KSZ * 4);

    prep_kernel<<<6144, 256, 0, stream>>>(Wih1, Whh1, bih1, bhh1, Wih2, Whh2,
                                          bih2, bhh2, Wc1, Wc2, bb1, bb2,
                                          h1b, h2b, c1, c2);
    transpose_key<<<4096, 256, 0, stream>>>(key_proj, keyT2);
    ce_gather<<<12800, 256, 0, stream>>>(text, emb, ce_f, ce_b);
    qproj_kernel<<<12800, 256, 0, stream>>>(ce_f, Wq, bq, qbuf);
    attn_kernel<<<2560, 256, 0, stream>>>(qbuf, keyT2, values, rlen, ctx_f, ctx_b);
    for (int i = 0; i <= L_SEQ; ++i)
        scan_phase<<<160, 256, 0, stream>>>(i, Wc1, Wc2, bb1, bb2, ce_b, ctx_b,
                                            h1b, h2b, c1, c2, h2_all);
    qproj_kernel<<<12800, 256, 0, stream>>>(h2_all, Wq, bq, qbuf);
    attn_kernel<<<2560, 256, 0, stream>>>(qbuf, keyT2, values, rlen, ctx_f, ctx_b);
    outpred_kernel<<<12800, 256, 0, stream>>>(h2_all, ctx_f, Wfc, bfc, emb, b_out, out);
}